// Round 1
// baseline (678.009 us; speedup 1.0000x reference)
//
#include <hip/hip_runtime.h>
#include <hip/hip_bf16.h>
#include <math.h>

#define N_NODES 20000
#define N_EDGES 640000
#define ET_EDGES (N_EDGES + N_NODES)   // with self-loops
#define G_GRAPHS 64
#define NEG_SLOPE 0.2f

// ---------------- CSR construction ----------------

__global__ void hist_dst(const int* __restrict__ ei, int* __restrict__ cnt) {
    int j = blockIdx.x * blockDim.x + threadIdx.x;
    if (j >= ET_EDGES) return;
    int d = (j < N_EDGES) ? ei[N_EDGES + j] : (j - N_EDGES);
    atomicAdd(&cnt[d], 1);
}

__global__ __launch_bounds__(1024) void scan_rowptr(const int* __restrict__ cnt,
                                                    int* __restrict__ row_ptr) {
    __shared__ int sums[1024];
    const int n = N_NODES;
    const int CH = (n + 1023) / 1024;   // 20
    int t = threadIdx.x;
    int base = t * CH;
    int s = 0;
    for (int i = 0; i < CH; ++i) {
        int idx = base + i;
        if (idx < n) s += cnt[idx];
    }
    sums[t] = s;
    __syncthreads();
    for (int o = 1; o < 1024; o <<= 1) {
        int v = (t >= o) ? sums[t - o] : 0;
        __syncthreads();
        sums[t] += v;
        __syncthreads();
    }
    int run = (t == 0) ? 0 : sums[t - 1];
    for (int i = 0; i < CH; ++i) {
        int idx = base + i;
        if (idx < n) { row_ptr[idx] = run; run += cnt[idx]; }
    }
    if (t == 1023) row_ptr[n] = sums[1023];
}

__global__ void fill_csr(const int* __restrict__ ei, const int* __restrict__ row_ptr,
                         int* __restrict__ cur, int* __restrict__ col) {
    int j = blockIdx.x * blockDim.x + threadIdx.x;
    if (j >= ET_EDGES) return;
    int s, d;
    if (j < N_EDGES) { s = ei[j]; d = ei[N_EDGES + j]; }
    else             { s = d = j - N_EDGES; }
    int pos = row_ptr[d] + atomicAdd(&cur[d], 1);
    col[pos] = s;
}

// ---------------- fp32 SGEMM: C[M,Nc] = A[M,K] @ B[K,Nc] ----------------
// 64x64 tile, BK=16, 256 threads, 4x4 per-thread microtile.

__global__ __launch_bounds__(256) void sgemm64(const float* __restrict__ A,
                                               const float* __restrict__ B,
                                               float* __restrict__ C,
                                               int M, int K, int Nc) {
    __shared__ float As[16][64];
    __shared__ float Bs[16][64];
    int bm = blockIdx.x * 64;
    int bn = blockIdx.y * 64;
    int t = threadIdx.x;
    int tr = t >> 2, tq = t & 3;       // A stage: row tr (0..63), k-quad tq
    int bkr = t >> 4, bnq = t & 15;    // B stage: k row (0..15), n-quad
    int tm = (t >> 4) * 4;             // compute: 16x16 thread grid
    int tn = (t & 15) * 4;
    float acc[4][4] = {};
    for (int k0 = 0; k0 < K; k0 += 16) {
        int ar = bm + tr;
        float4 av = make_float4(0.f, 0.f, 0.f, 0.f);
        if (ar < M) av = *(const float4*)&A[(size_t)ar * K + k0 + tq * 4];
        As[tq * 4 + 0][tr] = av.x;
        As[tq * 4 + 1][tr] = av.y;
        As[tq * 4 + 2][tr] = av.z;
        As[tq * 4 + 3][tr] = av.w;
        float4 bv = *(const float4*)&B[(size_t)(k0 + bkr) * Nc + bn + bnq * 4];
        *(float4*)&Bs[bkr][bnq * 4] = bv;
        __syncthreads();
        #pragma unroll
        for (int k = 0; k < 16; ++k) {
            float a[4], b[4];
            *(float4*)a = *(const float4*)&As[k][tm];
            *(float4*)b = *(const float4*)&Bs[k][tn];
            #pragma unroll
            for (int i = 0; i < 4; ++i)
                #pragma unroll
                for (int j = 0; j < 4; ++j)
                    acc[i][j] = fmaf(a[i], b[j], acc[i][j]);
        }
        __syncthreads();
    }
    #pragma unroll
    for (int i = 0; i < 4; ++i) {
        int r = bm + tm + i;
        if (r < M) {
            float4 o = make_float4(acc[i][0], acc[i][1], acc[i][2], acc[i][3]);
            *(float4*)&C[(size_t)r * Nc + bn + tn] = o;
        }
    }
}

// ---------------- per-node attention coefficients ----------------
// h: [N, HEADS*C]; a_src/a_dst: [HEADS*C]; out as_/ad_: [N, HEADS]

template <int HEADS, int C>
__global__ void node_alpha(const float* __restrict__ h,
                           const float* __restrict__ a_src,
                           const float* __restrict__ a_dst,
                           float* __restrict__ as_, float* __restrict__ ad_) {
    constexpr int F = HEADS * C;
    int v = blockIdx.x;
    int t = threadIdx.x;            // F threads
    float hv = h[(size_t)v * F + t];
    float ps = hv * a_src[t];
    float pd = hv * a_dst[t];
    #pragma unroll
    for (int o = 32; o; o >>= 1) {
        ps += __shfl_xor(ps, o);
        pd += __shfl_xor(pd, o);
    }
    __shared__ float ss[8], sd[8];
    int w = t >> 6;
    if ((t & 63) == 0) { ss[w] = ps; sd[w] = pd; }
    __syncthreads();
    if (t < HEADS) {
        constexpr int WPH = (C >= 64) ? (C / 64) : 1;  // waves per head
        float As = 0.f, Ad = 0.f;
        #pragma unroll
        for (int i = 0; i < WPH; ++i) { As += ss[t * WPH + i]; Ad += sd[t * WPH + i]; }
        as_[v * HEADS + t] = As;
        ad_[v * HEADS + t] = Ad;
    }
}

// ---------------- softmax-aggregate per dst node ----------------
// block = HEADS*C threads; wave-group per head (C=64) or 2 waves share head (C=128).

template <int HEADS, int C, bool DO_ELU>
__global__ void gat_aggregate(const float* __restrict__ h,
                              const float* __restrict__ as_,
                              const float* __restrict__ ad_,
                              const int* __restrict__ row_ptr,
                              const int* __restrict__ col,
                              const float* __restrict__ bias,
                              float* __restrict__ out) {
    constexpr int F = HEADS * C;
    int v = blockIdx.x;
    int t = threadIdx.x;
    int head = t / C;
    int lane = t & 63;
    int r0 = row_ptr[v], r1 = row_ptr[v + 1];
    float ad = ad_[v * HEADS + head];
    // pass 1: segment max (lane-parallel over edges, identical across waves of a head)
    float m = -INFINITY;
    for (int j = r0 + lane; j < r1; j += 64) {
        int s = col[j];
        float e = as_[s * HEADS + head] + ad;
        e = (e > 0.f) ? e : NEG_SLOPE * e;
        m = fmaxf(m, e);
    }
    #pragma unroll
    for (int o = 32; o; o >>= 1) m = fmaxf(m, __shfl_xor(m, o));
    // pass 2: weighted accumulate
    float acc = 0.f, l = 0.f;
    #pragma unroll 2
    for (int j = r0; j < r1; ++j) {
        int s = col[j];
        float e = as_[s * HEADS + head] + ad;
        e = (e > 0.f) ? e : NEG_SLOPE * e;
        float p = __expf(e - m);
        l += p;
        acc = fmaf(p, h[(size_t)s * F + t], acc);
    }
    float o = acc / (l + 1e-16f) + bias[t];
    if (DO_ELU) o = (o > 0.f) ? o : expm1f(o);
    out[(size_t)v * F + t] = o;
}

// ---------------- global mean pool (batch is sorted) ----------------

__global__ void batch_hist(const int* __restrict__ batch, int* __restrict__ gcnt) {
    int i = blockIdx.x * blockDim.x + threadIdx.x;
    if (i >= N_NODES) return;
    atomicAdd(&gcnt[batch[i]], 1);
}

__global__ void pool_mean(const float* __restrict__ hout, const int* __restrict__ gcnt,
                          float* __restrict__ gout) {
    int g = blockIdx.x;       // 64 blocks
    int c = threadIdx.x;      // 128 threads
    int off = 0;
    for (int i = 0; i < g; ++i) off += gcnt[i];
    int cnt = gcnt[g];
    float s = 0.f;
    #pragma unroll 4
    for (int i = 0; i < cnt; ++i) s += hout[(size_t)(off + i) * 128 + c];
    gout[g * 128 + c] = s / fmaxf((float)cnt, 1.0f);
}

// ---------------- launch ----------------

static inline size_t align_up(size_t x, size_t a) { return (x + a - 1) & ~(a - 1); }

extern "C" void kernel_launch(void* const* d_in, const int* in_sizes, int n_in,
                              void* d_out, int out_size, void* d_ws, size_t ws_size,
                              hipStream_t stream) {
    const float* x   = (const float*)d_in[0];
    const int*   ei  = (const int*)d_in[1];
    const int*   bat = (const int*)d_in[2];
    const float* W1  = (const float*)d_in[3];
    const float* as1 = (const float*)d_in[4];
    const float* ad1 = (const float*)d_in[5];
    const float* b1  = (const float*)d_in[6];
    const float* W2  = (const float*)d_in[7];
    const float* as2 = (const float*)d_in[8];
    const float* ad2 = (const float*)d_in[9];
    const float* b2  = (const float*)d_in[10];
    const float* W3  = (const float*)d_in[11];
    const float* as3 = (const float*)d_in[12];
    const float* ad3 = (const float*)d_in[13];
    const float* b3  = (const float*)d_in[14];

    float* gout = (float*)d_out;                     // [G,128]
    float* hout = (float*)d_out + G_GRAPHS * 128;    // [N,128]

    char* w = (char*)d_ws;
    size_t o = 0;
    float* bufA = (float*)(w + o); o = align_up(o + (size_t)N_NODES * 256 * 4, 256);
    float* bufB = (float*)(w + o); o = align_up(o + (size_t)N_NODES * 256 * 4, 256);
    float* asv  = (float*)(w + o); o = align_up(o + (size_t)N_NODES * 4 * 4, 256);
    float* adv  = (float*)(w + o); o = align_up(o + (size_t)N_NODES * 4 * 4, 256);
    int* row_ptr = (int*)(w + o);  o = align_up(o + (size_t)(N_NODES + 1) * 4, 256);
    int* col     = (int*)(w + o);  o = align_up(o + (size_t)ET_EDGES * 4, 256);
    int* cnt     = (int*)(w + o);  o = align_up(o + (size_t)N_NODES * 4, 256);
    int* cur     = (int*)(w + o);  o = align_up(o + (size_t)N_NODES * 4, 256);
    int* gcnt    = (int*)(w + o);  o = align_up(o + (size_t)G_GRAPHS * 4, 256);

    // ---- CSR build ----
    hipMemsetAsync(cnt, 0, (size_t)N_NODES * 4, stream);
    hipMemsetAsync(cur, 0, (size_t)N_NODES * 4, stream);
    hipMemsetAsync(gcnt, 0, (size_t)G_GRAPHS * 4, stream);
    hist_dst<<<(ET_EDGES + 255) / 256, 256, 0, stream>>>(ei, cnt);
    scan_rowptr<<<1, 1024, 0, stream>>>(cnt, row_ptr);
    fill_csr<<<(ET_EDGES + 255) / 256, 256, 0, stream>>>(ei, row_ptr, cur, col);

    dim3 g4(313, 4), g2(313, 2);

    // ---- layer 1: 128 -> 4x64 ----
    sgemm64<<<g4, 256, 0, stream>>>(x, W1, bufA, N_NODES, 128, 256);
    node_alpha<4, 64><<<N_NODES, 256, 0, stream>>>(bufA, as1, ad1, asv, adv);
    gat_aggregate<4, 64, true><<<N_NODES, 256, 0, stream>>>(bufA, asv, adv, row_ptr, col, b1, bufB);

    // ---- layer 2: 256 -> 4x64 ----
    sgemm64<<<g4, 256, 0, stream>>>(bufB, W2, bufA, N_NODES, 256, 256);
    node_alpha<4, 64><<<N_NODES, 256, 0, stream>>>(bufA, as2, ad2, asv, adv);
    gat_aggregate<4, 64, true><<<N_NODES, 256, 0, stream>>>(bufA, asv, adv, row_ptr, col, b2, bufB);

    // ---- layer 3: 256 -> 128 (1 head, no concat, no elu) ----
    sgemm64<<<g2, 256, 0, stream>>>(bufB, W3, bufA, N_NODES, 256, 128);
    node_alpha<1, 128><<<N_NODES, 128, 0, stream>>>(bufA, as3, ad3, asv, adv);
    gat_aggregate<1, 128, false><<<N_NODES, 128, 0, stream>>>(bufA, asv, adv, row_ptr, col, b3, hout);

    // ---- global mean pool ----
    batch_hist<<<(N_NODES + 255) / 256, 256, 0, stream>>>(bat, gcnt);
    pool_mean<<<G_GRAPHS, 128, 0, stream>>>(hout, gcnt, gout);
}

// Round 2
// 620.317 us; speedup vs baseline: 1.0930x; 1.0930x over previous
//
#include <hip/hip_runtime.h>
#include <hip/hip_bf16.h>
#include <math.h>

#define N_NODES 20000
#define N_EDGES 640000
#define ET_EDGES (N_EDGES + N_NODES)   // with self-loops
#define G_GRAPHS 64
#define NEG_SLOPE 0.2f

// ---------------- CSR construction ----------------

__global__ void hist_dst(const int* __restrict__ ei, int* __restrict__ cnt) {
    int j = blockIdx.x * blockDim.x + threadIdx.x;
    if (j >= ET_EDGES) return;
    int d = (j < N_EDGES) ? ei[N_EDGES + j] : (j - N_EDGES);
    atomicAdd(&cnt[d], 1);
}

__global__ __launch_bounds__(1024) void scan_rowptr(const int* __restrict__ cnt,
                                                    int* __restrict__ row_ptr) {
    __shared__ int sums[1024];
    const int n = N_NODES;
    const int CH = (n + 1023) / 1024;   // 20
    int t = threadIdx.x;
    int base = t * CH;
    int s = 0;
    for (int i = 0; i < CH; ++i) {
        int idx = base + i;
        if (idx < n) s += cnt[idx];
    }
    sums[t] = s;
    __syncthreads();
    for (int o = 1; o < 1024; o <<= 1) {
        int v = (t >= o) ? sums[t - o] : 0;
        __syncthreads();
        sums[t] += v;
        __syncthreads();
    }
    int run = (t == 0) ? 0 : sums[t - 1];
    for (int i = 0; i < CH; ++i) {
        int idx = base + i;
        if (idx < n) { row_ptr[idx] = run; run += cnt[idx]; }
    }
    if (t == 1023) row_ptr[n] = sums[1023];
}

__global__ void fill_csr(const int* __restrict__ ei, const int* __restrict__ row_ptr,
                         int* __restrict__ cur, int* __restrict__ col) {
    int j = blockIdx.x * blockDim.x + threadIdx.x;
    if (j >= ET_EDGES) return;
    int s, d;
    if (j < N_EDGES) { s = ei[j]; d = ei[N_EDGES + j]; }
    else             { s = d = j - N_EDGES; }
    int pos = row_ptr[d] + atomicAdd(&cur[d], 1);
    col[pos] = s;
}

// ---------------- fp32 SGEMM: C[M,Nc] = A[M,K] @ B[K,Nc] ----------------
// 64x64 tile, BK=16, 256 threads, 4x4 per-thread microtile.

__global__ __launch_bounds__(256) void sgemm64(const float* __restrict__ A,
                                               const float* __restrict__ B,
                                               float* __restrict__ C,
                                               int M, int K, int Nc) {
    __shared__ float As[16][64];
    __shared__ float Bs[16][64];
    int bm = blockIdx.x * 64;
    int bn = blockIdx.y * 64;
    int t = threadIdx.x;
    int tr = t >> 2, tq = t & 3;       // A stage: row tr (0..63), k-quad tq
    int bkr = t >> 4, bnq = t & 15;    // B stage: k row (0..15), n-quad
    int tm = (t >> 4) * 4;             // compute: 16x16 thread grid
    int tn = (t & 15) * 4;
    float acc[4][4] = {};
    for (int k0 = 0; k0 < K; k0 += 16) {
        int ar = bm + tr;
        float4 av = make_float4(0.f, 0.f, 0.f, 0.f);
        if (ar < M) av = *(const float4*)&A[(size_t)ar * K + k0 + tq * 4];
        As[tq * 4 + 0][tr] = av.x;
        As[tq * 4 + 1][tr] = av.y;
        As[tq * 4 + 2][tr] = av.z;
        As[tq * 4 + 3][tr] = av.w;
        float4 bv = *(const float4*)&B[(size_t)(k0 + bkr) * Nc + bn + bnq * 4];
        *(float4*)&Bs[bkr][bnq * 4] = bv;
        __syncthreads();
        #pragma unroll
        for (int k = 0; k < 16; ++k) {
            float a[4], b[4];
            *(float4*)a = *(const float4*)&As[k][tm];
            *(float4*)b = *(const float4*)&Bs[k][tn];
            #pragma unroll
            for (int i = 0; i < 4; ++i)
                #pragma unroll
                for (int j = 0; j < 4; ++j)
                    acc[i][j] = fmaf(a[i], b[j], acc[i][j]);
        }
        __syncthreads();
    }
    #pragma unroll
    for (int i = 0; i < 4; ++i) {
        int r = bm + tm + i;
        if (r < M) {
            float4 o = make_float4(acc[i][0], acc[i][1], acc[i][2], acc[i][3]);
            *(float4*)&C[(size_t)r * Nc + bn + tn] = o;
        }
    }
}

// ---------------- per-node attention coefficients ----------------
// 4 nodes per 256-thread block, one wave per node, VEC floats per lane.

template <int HEADS, int C>
__global__ __launch_bounds__(256) void node_alpha2(const float* __restrict__ h,
                                                   const float* __restrict__ a_src,
                                                   const float* __restrict__ a_dst,
                                                   float* __restrict__ as_,
                                                   float* __restrict__ ad_) {
    constexpr int F = HEADS * C;
    constexpr int VEC = F / 64;        // 4 (F=256) or 2 (F=128)
    constexpr int LPH = C / VEC;       // lanes per head: 16 or 64
    int wid = threadIdx.x >> 6, lane = threadIdx.x & 63;
    int v = blockIdx.x * 4 + wid;
    if (v >= N_NODES) return;
    const float* hp = h + (size_t)v * F + lane * VEC;
    float ps = 0.f, pd = 0.f;
    #pragma unroll
    for (int c = 0; c < VEC; ++c) {
        float hv = hp[c];
        ps = fmaf(hv, a_src[lane * VEC + c], ps);
        pd = fmaf(hv, a_dst[lane * VEC + c], pd);
    }
    #pragma unroll
    for (int o = LPH / 2; o; o >>= 1) {
        ps += __shfl_xor(ps, o);
        pd += __shfl_xor(pd, o);
    }
    if ((lane & (LPH - 1)) == 0) {
        int head = lane / LPH;
        as_[v * HEADS + head] = ps;
        ad_[v * HEADS + head] = pd;
    }
}

// ---------------- softmax-aggregate: one wave per dst node ----------------
// Lane-parallel weight compute per 64-edge chunk (staged in LDS), then a
// broadcast inner loop where each lane gathers VEC contiguous channels
// (float4/float2) of h[src]. No segment-max: |e| <~ 2 so exp(e) is safe and
// exp(e)/sum(exp(e)) == softmax exactly (up to fp reassociation).

template <int HEADS, int C, bool DO_ELU>
__global__ __launch_bounds__(256) void gat_aggregate2(
        const float* __restrict__ h,      // [N, F]
        const float* __restrict__ as_,    // [N, HEADS]
        const float* __restrict__ ad_,    // [N, HEADS]
        const int* __restrict__ row_ptr,
        const int* __restrict__ col,
        const float* __restrict__ bias,   // [F]
        float* __restrict__ out) {        // [N, F]
    constexpr int F = HEADS * C;
    constexpr int VEC = F / 64;           // 4 or 2
    constexpr int WAVES = 4;
    __shared__ int   s_off[WAVES][64];
    __shared__ float s_p[WAVES][64 * HEADS];
    int wid = threadIdx.x >> 6, lane = threadIdx.x & 63;
    int v = blockIdx.x * WAVES + wid;
    if (v >= N_NODES) return;
    int head = (lane * VEC) / C;          // 4-head: lane/16 ; 1-head: 0
    int r0 = row_ptr[v], r1 = row_ptr[v + 1];
    float adh[HEADS];
    #pragma unroll
    for (int hh = 0; hh < HEADS; ++hh) adh[hh] = ad_[v * HEADS + hh];
    float acc[VEC] = {};
    float lsum[HEADS] = {};
    const char* hbl = (const char*)h + lane * VEC * 4;   // lane-offset base

    for (int base = r0; base < r1; base += 64) {
        int j = base + lane;
        bool valid = j < r1;
        int s = col[valid ? j : r0];
        float p[HEADS];
        if (HEADS == 4) {
            float4 av = *(const float4*)&as_[s * 4];
            float ev[4] = {av.x, av.y, av.z, av.w};
            #pragma unroll
            for (int hh = 0; hh < 4; ++hh) {
                float e = ev[hh] + adh[hh];
                e = (e > 0.f) ? e : NEG_SLOPE * e;
                p[hh] = valid ? __expf(e) : 0.f;
                lsum[hh] += p[hh];
            }
            *(float4*)&s_p[wid][lane * 4] = make_float4(p[0], p[1], p[2], p[3]);
        } else {
            float e = as_[s] + adh[0];
            e = (e > 0.f) ? e : NEG_SLOPE * e;
            p[0] = valid ? __expf(e) : 0.f;
            lsum[0] += p[0];
            s_p[wid][lane] = p[0];
        }
        s_off[wid][lane] = s * (F * 4);   // byte offset of row s

        int nk = min(64, r1 - base);
        #pragma unroll 4
        for (int k = 0; k < nk; ++k) {
            int off = s_off[wid][k];                       // broadcast
            float pk = s_p[wid][k * HEADS + head];         // broadcast x16
            const float* hp = (const float*)(hbl + off);
            if (VEC == 4) {
                float4 hv = *(const float4*)hp;
                acc[0] = fmaf(pk, hv.x, acc[0]);
                acc[1] = fmaf(pk, hv.y, acc[1]);
                acc[2] = fmaf(pk, hv.z, acc[2]);
                acc[3] = fmaf(pk, hv.w, acc[3]);
            } else {
                float2 hv = *(const float2*)hp;
                acc[0] = fmaf(pk, hv.x, acc[0]);
                acc[1] = fmaf(pk, hv.y, acc[1]);
            }
        }
    }
    // reduce lsum across the wave (each lane has partial over its chunk edges)
    #pragma unroll
    for (int hh = 0; hh < HEADS; ++hh) {
        #pragma unroll
        for (int o = 32; o; o >>= 1) lsum[hh] += __shfl_xor(lsum[hh], o);
    }
    float l = lsum[0];
    if (HEADS == 4) {
        l = (head == 0) ? lsum[0] : (head == 1) ? lsum[1] : (head == 2) ? lsum[2] : lsum[3];
    }
    float inv = 1.f / (l + 1e-16f);
    #pragma unroll
    for (int c = 0; c < VEC; ++c) {
        float o = acc[c] * inv + bias[lane * VEC + c];
        if (DO_ELU) o = (o > 0.f) ? o : expm1f(o);
        out[(size_t)v * F + lane * VEC + c] = o;
    }
}

// ---------------- global mean pool (batch is sorted) ----------------

__global__ void batch_hist(const int* __restrict__ batch, int* __restrict__ gcnt) {
    int i = blockIdx.x * blockDim.x + threadIdx.x;
    if (i >= N_NODES) return;
    atomicAdd(&gcnt[batch[i]], 1);
}

__global__ void pool_mean(const float* __restrict__ hout, const int* __restrict__ gcnt,
                          float* __restrict__ gout) {
    int g = blockIdx.x;       // 64 blocks
    int c = threadIdx.x;      // 128 threads
    int off = 0;
    for (int i = 0; i < g; ++i) off += gcnt[i];
    int cnt = gcnt[g];
    float s = 0.f;
    #pragma unroll 4
    for (int i = 0; i < cnt; ++i) s += hout[(size_t)(off + i) * 128 + c];
    gout[g * 128 + c] = s / fmaxf((float)cnt, 1.0f);
}

// ---------------- launch ----------------

static inline size_t align_up(size_t x, size_t a) { return (x + a - 1) & ~(a - 1); }

extern "C" void kernel_launch(void* const* d_in, const int* in_sizes, int n_in,
                              void* d_out, int out_size, void* d_ws, size_t ws_size,
                              hipStream_t stream) {
    const float* x   = (const float*)d_in[0];
    const int*   ei  = (const int*)d_in[1];
    const int*   bat = (const int*)d_in[2];
    const float* W1  = (const float*)d_in[3];
    const float* as1 = (const float*)d_in[4];
    const float* ad1 = (const float*)d_in[5];
    const float* b1  = (const float*)d_in[6];
    const float* W2  = (const float*)d_in[7];
    const float* as2 = (const float*)d_in[8];
    const float* ad2 = (const float*)d_in[9];
    const float* b2  = (const float*)d_in[10];
    const float* W3  = (const float*)d_in[11];
    const float* as3 = (const float*)d_in[12];
    const float* ad3 = (const float*)d_in[13];
    const float* b3  = (const float*)d_in[14];

    float* gout = (float*)d_out;                     // [G,128]
    float* hout = (float*)d_out + G_GRAPHS * 128;    // [N,128]

    char* w = (char*)d_ws;
    size_t o = 0;
    float* bufA = (float*)(w + o); o = align_up(o + (size_t)N_NODES * 256 * 4, 256);
    float* bufB = (float*)(w + o); o = align_up(o + (size_t)N_NODES * 256 * 4, 256);
    float* asv  = (float*)(w + o); o = align_up(o + (size_t)N_NODES * 4 * 4, 256);
    float* adv  = (float*)(w + o); o = align_up(o + (size_t)N_NODES * 4 * 4, 256);
    int* row_ptr = (int*)(w + o);  o = align_up(o + (size_t)(N_NODES + 1) * 4, 256);
    int* col     = (int*)(w + o);  o = align_up(o + (size_t)ET_EDGES * 4, 256);
    int* cnt     = (int*)(w + o);  o = align_up(o + (size_t)N_NODES * 4, 256);
    int* cur     = (int*)(w + o);  o = align_up(o + (size_t)N_NODES * 4, 256);
    int* gcnt    = (int*)(w + o);  o = align_up(o + (size_t)G_GRAPHS * 4, 256);

    // ---- CSR build ----
    hipMemsetAsync(cnt, 0, (size_t)N_NODES * 4, stream);
    hipMemsetAsync(cur, 0, (size_t)N_NODES * 4, stream);
    hipMemsetAsync(gcnt, 0, (size_t)G_GRAPHS * 4, stream);
    hist_dst<<<(ET_EDGES + 255) / 256, 256, 0, stream>>>(ei, cnt);
    scan_rowptr<<<1, 1024, 0, stream>>>(cnt, row_ptr);
    fill_csr<<<(ET_EDGES + 255) / 256, 256, 0, stream>>>(ei, row_ptr, cur, col);

    dim3 g4(313, 4), g2(313, 2);
    int nb = (N_NODES + 3) / 4;   // 4 nodes per block

    // ---- layer 1: 128 -> 4x64 ----
    sgemm64<<<g4, 256, 0, stream>>>(x, W1, bufA, N_NODES, 128, 256);
    node_alpha2<4, 64><<<nb, 256, 0, stream>>>(bufA, as1, ad1, asv, adv);
    gat_aggregate2<4, 64, true><<<nb, 256, 0, stream>>>(bufA, asv, adv, row_ptr, col, b1, bufB);

    // ---- layer 2: 256 -> 4x64 ----
    sgemm64<<<g4, 256, 0, stream>>>(bufB, W2, bufA, N_NODES, 256, 256);
    node_alpha2<4, 64><<<nb, 256, 0, stream>>>(bufA, as2, ad2, asv, adv);
    gat_aggregate2<4, 64, true><<<nb, 256, 0, stream>>>(bufA, asv, adv, row_ptr, col, b2, bufB);

    // ---- layer 3: 256 -> 128 (1 head, no concat, no elu) ----
    sgemm64<<<g2, 256, 0, stream>>>(bufB, W3, bufA, N_NODES, 256, 128);
    node_alpha2<1, 128><<<nb, 256, 0, stream>>>(bufA, as3, ad3, asv, adv);
    gat_aggregate2<1, 128, false><<<nb, 256, 0, stream>>>(bufA, asv, adv, row_ptr, col, b3, hout);

    // ---- global mean pool ----
    batch_hist<<<(N_NODES + 255) / 256, 256, 0, stream>>>(bat, gcnt);
    pool_mean<<<G_GRAPHS, 128, 0, stream>>>(hout, gcnt, gout);
}

// Round 3
// 528.659 us; speedup vs baseline: 1.2825x; 1.1734x over previous
//
#include <hip/hip_runtime.h>
#include <hip/hip_bf16.h>
#include <math.h>

#define N_NODES 20000
#define N_EDGES 640000
#define ET_EDGES (N_EDGES + N_NODES)   // with self-loops
#define G_GRAPHS 64
#define NEG_SLOPE 0.2f

// ---------------- CSR construction ----------------

__global__ void hist_dst(const int* __restrict__ ei, int* __restrict__ cnt) {
    int j = blockIdx.x * blockDim.x + threadIdx.x;
    if (j >= ET_EDGES) return;
    int d = (j < N_EDGES) ? ei[N_EDGES + j] : (j - N_EDGES);
    atomicAdd(&cnt[d], 1);
}

__global__ __launch_bounds__(1024) void scan_rowptr(const int* __restrict__ cnt,
                                                    int* __restrict__ row_ptr) {
    __shared__ int sums[1024];
    const int n = N_NODES;
    const int CH = (n + 1023) / 1024;   // 20
    int t = threadIdx.x;
    int base = t * CH;
    int s = 0;
    for (int i = 0; i < CH; ++i) {
        int idx = base + i;
        if (idx < n) s += cnt[idx];
    }
    sums[t] = s;
    __syncthreads();
    for (int o = 1; o < 1024; o <<= 1) {
        int v = (t >= o) ? sums[t - o] : 0;
        __syncthreads();
        sums[t] += v;
        __syncthreads();
    }
    int run = (t == 0) ? 0 : sums[t - 1];
    for (int i = 0; i < CH; ++i) {
        int idx = base + i;
        if (idx < n) { row_ptr[idx] = run; run += cnt[idx]; }
    }
    if (t == 1023) row_ptr[n] = sums[1023];
}

__global__ void fill_csr(const int* __restrict__ ei, const int* __restrict__ row_ptr,
                         int* __restrict__ cur, int* __restrict__ col) {
    int j = blockIdx.x * blockDim.x + threadIdx.x;
    if (j >= ET_EDGES) return;
    int s, d;
    if (j < N_EDGES) { s = ei[j]; d = ei[N_EDGES + j]; }
    else             { s = d = j - N_EDGES; }
    int pos = row_ptr[d] + atomicAdd(&cur[d], 1);
    col[pos] = s;
}

// ---------------- fp32 SGEMM: C[M,Nc] = A[M,K] @ B[K,Nc] ----------------
// 64x64 tile, BK=16, 256 threads, 4x4 per-thread microtile.

__global__ __launch_bounds__(256) void sgemm64(const float* __restrict__ A,
                                               const float* __restrict__ B,
                                               float* __restrict__ C,
                                               int M, int K, int Nc) {
    __shared__ float As[16][64];
    __shared__ float Bs[16][64];
    int bm = blockIdx.x * 64;
    int bn = blockIdx.y * 64;
    int t = threadIdx.x;
    int tr = t >> 2, tq = t & 3;       // A stage: row tr (0..63), k-quad tq
    int bkr = t >> 4, bnq = t & 15;    // B stage: k row (0..15), n-quad
    int tm = (t >> 4) * 4;             // compute: 16x16 thread grid
    int tn = (t & 15) * 4;
    float acc[4][4] = {};
    for (int k0 = 0; k0 < K; k0 += 16) {
        int ar = bm + tr;
        float4 av = make_float4(0.f, 0.f, 0.f, 0.f);
        if (ar < M) av = *(const float4*)&A[(size_t)ar * K + k0 + tq * 4];
        As[tq * 4 + 0][tr] = av.x;
        As[tq * 4 + 1][tr] = av.y;
        As[tq * 4 + 2][tr] = av.z;
        As[tq * 4 + 3][tr] = av.w;
        float4 bv = *(const float4*)&B[(size_t)(k0 + bkr) * Nc + bn + bnq * 4];
        *(float4*)&Bs[bkr][bnq * 4] = bv;
        __syncthreads();
        #pragma unroll
        for (int k = 0; k < 16; ++k) {
            float a[4], b[4];
            *(float4*)a = *(const float4*)&As[k][tm];
            *(float4*)b = *(const float4*)&Bs[k][tn];
            #pragma unroll
            for (int i = 0; i < 4; ++i)
                #pragma unroll
                for (int j = 0; j < 4; ++j)
                    acc[i][j] = fmaf(a[i], b[j], acc[i][j]);
        }
        __syncthreads();
    }
    #pragma unroll
    for (int i = 0; i < 4; ++i) {
        int r = bm + tm + i;
        if (r < M) {
            float4 o = make_float4(acc[i][0], acc[i][1], acc[i][2], acc[i][3]);
            *(float4*)&C[(size_t)r * Nc + bn + tn] = o;
        }
    }
}

// ---------------- per-node attention coefficients ----------------
// 4 nodes per 256-thread block, one wave per node, VEC floats per lane.

template <int HEADS, int C>
__global__ __launch_bounds__(256) void node_alpha2(const float* __restrict__ h,
                                                   const float* __restrict__ a_src,
                                                   const float* __restrict__ a_dst,
                                                   float* __restrict__ as_,
                                                   float* __restrict__ ad_) {
    constexpr int F = HEADS * C;
    constexpr int VEC = F / 64;        // 4 (F=256) or 2 (F=128)
    constexpr int LPH = C / VEC;       // lanes per head: 16 or 64
    int wid = threadIdx.x >> 6, lane = threadIdx.x & 63;
    int v = blockIdx.x * 4 + wid;
    if (v >= N_NODES) return;
    const float* hp = h + (size_t)v * F + lane * VEC;
    float ps = 0.f, pd = 0.f;
    #pragma unroll
    for (int c = 0; c < VEC; ++c) {
        float hv = hp[c];
        ps = fmaf(hv, a_src[lane * VEC + c], ps);
        pd = fmaf(hv, a_dst[lane * VEC + c], pd);
    }
    #pragma unroll
    for (int o = LPH / 2; o; o >>= 1) {
        ps += __shfl_xor(ps, o);
        pd += __shfl_xor(pd, o);
    }
    if ((lane & (LPH - 1)) == 0) {
        int head = lane / LPH;
        as_[v * HEADS + head] = ps;
        ad_[v * HEADS + head] = pd;
    }
}

// ---------------- softmax-aggregate: one wave per dst node ----------------

template <int HEADS, int C, bool DO_ELU>
__global__ __launch_bounds__(256) void gat_aggregate2(
        const float* __restrict__ h,      // [N, F]
        const float* __restrict__ as_,    // [N, HEADS]
        const float* __restrict__ ad_,    // [N, HEADS]
        const int* __restrict__ row_ptr,
        const int* __restrict__ col,
        const float* __restrict__ bias,   // [F]
        float* __restrict__ out) {        // [N, F]
    constexpr int F = HEADS * C;
    constexpr int VEC = F / 64;           // 4 or 2
    constexpr int WAVES = 4;
    __shared__ int   s_off[WAVES][64];
    __shared__ float s_p[WAVES][64 * HEADS];
    int wid = threadIdx.x >> 6, lane = threadIdx.x & 63;
    int v = blockIdx.x * WAVES + wid;
    if (v >= N_NODES) return;
    int head = (lane * VEC) / C;          // 4-head: lane/16 ; 1-head: 0
    int r0 = row_ptr[v], r1 = row_ptr[v + 1];
    float adh[HEADS];
    #pragma unroll
    for (int hh = 0; hh < HEADS; ++hh) adh[hh] = ad_[v * HEADS + hh];
    float acc[VEC] = {};
    float lsum[HEADS] = {};
    const char* hbl = (const char*)h + lane * VEC * 4;   // lane-offset base

    for (int base = r0; base < r1; base += 64) {
        int j = base + lane;
        bool valid = j < r1;
        int s = col[valid ? j : r0];
        float p[HEADS];
        if (HEADS == 4) {
            float4 av = *(const float4*)&as_[s * 4];
            float ev[4] = {av.x, av.y, av.z, av.w};
            #pragma unroll
            for (int hh = 0; hh < 4; ++hh) {
                float e = ev[hh] + adh[hh];
                e = (e > 0.f) ? e : NEG_SLOPE * e;
                p[hh] = valid ? __expf(e) : 0.f;
                lsum[hh] += p[hh];
            }
            *(float4*)&s_p[wid][lane * 4] = make_float4(p[0], p[1], p[2], p[3]);
        } else {
            float e = as_[s] + adh[0];
            e = (e > 0.f) ? e : NEG_SLOPE * e;
            p[0] = valid ? __expf(e) : 0.f;
            lsum[0] += p[0];
            s_p[wid][lane] = p[0];
        }
        s_off[wid][lane] = s * (F * 4);   // byte offset of row s

        int nk = min(64, r1 - base);
        #pragma unroll 4
        for (int k = 0; k < nk; ++k) {
            int off = s_off[wid][k];                       // broadcast
            float pk = s_p[wid][k * HEADS + head];         // broadcast x16
            const float* hp = (const float*)(hbl + off);
            if (VEC == 4) {
                float4 hv = *(const float4*)hp;
                acc[0] = fmaf(pk, hv.x, acc[0]);
                acc[1] = fmaf(pk, hv.y, acc[1]);
                acc[2] = fmaf(pk, hv.z, acc[2]);
                acc[3] = fmaf(pk, hv.w, acc[3]);
            } else {
                float2 hv = *(const float2*)hp;
                acc[0] = fmaf(pk, hv.x, acc[0]);
                acc[1] = fmaf(pk, hv.y, acc[1]);
            }
        }
    }
    #pragma unroll
    for (int hh = 0; hh < HEADS; ++hh) {
        #pragma unroll
        for (int o = 32; o; o >>= 1) lsum[hh] += __shfl_xor(lsum[hh], o);
    }
    float l = lsum[0];
    if (HEADS == 4) {
        l = (head == 0) ? lsum[0] : (head == 1) ? lsum[1] : (head == 2) ? lsum[2] : lsum[3];
    }
    float inv = 1.f / (l + 1e-16f);
    #pragma unroll
    for (int c = 0; c < VEC; ++c) {
        float o = acc[c] * inv + bias[lane * VEC + c];
        if (DO_ELU) o = (o > 0.f) ? o : expm1f(o);
        out[(size_t)v * F + lane * VEC + c] = o;
    }
}

// ---------------- global mean pool (batch sorted -> binary search bounds) ----

__global__ void graph_bounds(const int* __restrict__ batch, int* __restrict__ gstart) {
    int g = threadIdx.x;               // 0..64 inclusive
    if (g > G_GRAPHS) return;
    int lo = 0, hi = N_NODES;
    while (lo < hi) {                  // first i with batch[i] >= g
        int mid = (lo + hi) >> 1;
        if (batch[mid] < g) lo = mid + 1; else hi = mid;
    }
    gstart[g] = lo;
}

__global__ void pool_mean(const float* __restrict__ hout, const int* __restrict__ gstart,
                          float* __restrict__ gout) {
    int g = blockIdx.x;       // 64 blocks
    int c = threadIdx.x;      // 128 threads
    int off = gstart[g], end = gstart[g + 1];
    float s = 0.f;
    #pragma unroll 4
    for (int i = off; i < end; ++i) s += hout[(size_t)i * 128 + c];
    gout[g * 128 + c] = s / fmaxf((float)(end - off), 1.0f);
}

// ---------------- launch ----------------

static inline size_t align_up(size_t x, size_t a) { return (x + a - 1) & ~(a - 1); }

extern "C" void kernel_launch(void* const* d_in, const int* in_sizes, int n_in,
                              void* d_out, int out_size, void* d_ws, size_t ws_size,
                              hipStream_t stream) {
    const float* x   = (const float*)d_in[0];
    const int*   ei  = (const int*)d_in[1];
    const int*   bat = (const int*)d_in[2];
    const float* W1  = (const float*)d_in[3];
    const float* as1 = (const float*)d_in[4];
    const float* ad1 = (const float*)d_in[5];
    const float* b1  = (const float*)d_in[6];
    const float* W2  = (const float*)d_in[7];
    const float* as2 = (const float*)d_in[8];
    const float* ad2 = (const float*)d_in[9];
    const float* b2  = (const float*)d_in[10];
    const float* W3  = (const float*)d_in[11];
    const float* as3 = (const float*)d_in[12];
    const float* ad3 = (const float*)d_in[13];
    const float* b3  = (const float*)d_in[14];

    float* gout = (float*)d_out;                     // [G,128]
    float* hout = (float*)d_out + G_GRAPHS * 128;    // [N,128]

    char* w = (char*)d_ws;
    size_t o = 0;
    float* bufA = (float*)(w + o); o = align_up(o + (size_t)N_NODES * 256 * 4, 256);
    float* bufB = (float*)(w + o); o = align_up(o + (size_t)N_NODES * 256 * 4, 256);
    float* asv  = (float*)(w + o); o = align_up(o + (size_t)N_NODES * 4 * 4, 256);
    float* adv  = (float*)(w + o); o = align_up(o + (size_t)N_NODES * 4 * 4, 256);
    int* row_ptr = (int*)(w + o);  o = align_up(o + (size_t)(N_NODES + 1) * 4, 256);
    int* col     = (int*)(w + o);  o = align_up(o + (size_t)ET_EDGES * 4, 256);
    int* cnt     = (int*)(w + o);  o = align_up(o + (size_t)N_NODES * 4, 256);
    int* cur     = (int*)(w + o);  o = align_up(o + (size_t)N_NODES * 4, 256);
    int* gstart  = (int*)(w + o);  o = align_up(o + (size_t)(G_GRAPHS + 1) * 4, 256);

    // ---- CSR build ----
    hipMemsetAsync(cnt, 0, (size_t)N_NODES * 4, stream);
    hipMemsetAsync(cur, 0, (size_t)N_NODES * 4, stream);
    hist_dst<<<(ET_EDGES + 255) / 256, 256, 0, stream>>>(ei, cnt);
    scan_rowptr<<<1, 1024, 0, stream>>>(cnt, row_ptr);
    fill_csr<<<(ET_EDGES + 255) / 256, 256, 0, stream>>>(ei, row_ptr, cur, col);
    graph_bounds<<<1, 128, 0, stream>>>(bat, gstart);

    dim3 g4(313, 4), g2(313, 2);
    int nb = (N_NODES + 3) / 4;   // 4 nodes per block

    // ---- layer 1: 128 -> 4x64 ----
    sgemm64<<<g4, 256, 0, stream>>>(x, W1, bufA, N_NODES, 128, 256);
    node_alpha2<4, 64><<<nb, 256, 0, stream>>>(bufA, as1, ad1, asv, adv);
    gat_aggregate2<4, 64, true><<<nb, 256, 0, stream>>>(bufA, asv, adv, row_ptr, col, b1, bufB);

    // ---- layer 2: 256 -> 4x64 ----
    sgemm64<<<g4, 256, 0, stream>>>(bufB, W2, bufA, N_NODES, 256, 256);
    node_alpha2<4, 64><<<nb, 256, 0, stream>>>(bufA, as2, ad2, asv, adv);
    gat_aggregate2<4, 64, true><<<nb, 256, 0, stream>>>(bufA, asv, adv, row_ptr, col, b2, bufB);

    // ---- layer 3: 256 -> 128 (1 head, no concat, no elu) ----
    sgemm64<<<g2, 256, 0, stream>>>(bufB, W3, bufA, N_NODES, 256, 128);
    node_alpha2<1, 128><<<nb, 256, 0, stream>>>(bufA, as3, ad3, asv, adv);
    gat_aggregate2<1, 128, false><<<nb, 256, 0, stream>>>(bufA, asv, adv, row_ptr, col, b3, hout);

    // ---- global mean pool ----
    pool_mean<<<G_GRAPHS, 128, 0, stream>>>(hout, gstart, gout);
}

// Round 4
// 519.807 us; speedup vs baseline: 1.3043x; 1.0170x over previous
//
#include <hip/hip_runtime.h>
#include <hip/hip_bf16.h>
#include <math.h>

#define N_NODES 20000
#define N_EDGES 640000
#define ET_EDGES (N_EDGES + N_NODES)   // with self-loops
#define G_GRAPHS 64
#define NEG_SLOPE 0.2f

// ---------------- CSR construction (+ graph bounds folded in) ----------------

__global__ void hist_dst(const int* __restrict__ ei, int* __restrict__ cnt,
                         const int* __restrict__ batch, int* __restrict__ gstart) {
    int j = blockIdx.x * blockDim.x + threadIdx.x;
    if (blockIdx.x == 0 && threadIdx.x <= G_GRAPHS) {
        int g = threadIdx.x;
        int lo = 0, hi = N_NODES;
        while (lo < hi) {              // first i with batch[i] >= g
            int mid = (lo + hi) >> 1;
            if (batch[mid] < g) lo = mid + 1; else hi = mid;
        }
        gstart[g] = lo;
    }
    if (j >= ET_EDGES) return;
    int d = (j < N_EDGES) ? ei[N_EDGES + j] : (j - N_EDGES);
    atomicAdd(&cnt[d], 1);
}

__global__ __launch_bounds__(1024) void scan_rowptr(const int* __restrict__ cnt,
                                                    int* __restrict__ row_ptr) {
    __shared__ int sums[1024];
    const int n = N_NODES;
    const int CH = (n + 1023) / 1024;   // 20
    int t = threadIdx.x;
    int base = t * CH;
    int s = 0;
    for (int i = 0; i < CH; ++i) {
        int idx = base + i;
        if (idx < n) s += cnt[idx];
    }
    sums[t] = s;
    __syncthreads();
    for (int o = 1; o < 1024; o <<= 1) {
        int v = (t >= o) ? sums[t - o] : 0;
        __syncthreads();
        sums[t] += v;
        __syncthreads();
    }
    int run = (t == 0) ? 0 : sums[t - 1];
    for (int i = 0; i < CH; ++i) {
        int idx = base + i;
        if (idx < n) { row_ptr[idx] = run; run += cnt[idx]; }
    }
    if (t == 1023) row_ptr[n] = sums[1023];
}

__global__ void fill_csr(const int* __restrict__ ei, const int* __restrict__ row_ptr,
                         int* __restrict__ cur, int* __restrict__ col) {
    int j = blockIdx.x * blockDim.x + threadIdx.x;
    if (j >= ET_EDGES) return;
    int s, d;
    if (j < N_EDGES) { s = ei[j]; d = ei[N_EDGES + j]; }
    else             { s = d = j - N_EDGES; }
    int pos = row_ptr[d] + atomicAdd(&cur[d], 1);
    col[pos] = s;
}

// ---------------- fp32 SGEMM: C[M,Nc] = A[M,K] @ B[K,Nc] ----------------

__global__ __launch_bounds__(256) void sgemm64(const float* __restrict__ A,
                                               const float* __restrict__ B,
                                               float* __restrict__ C,
                                               int M, int K, int Nc) {
    __shared__ float As[16][64];
    __shared__ float Bs[16][64];
    int bm = blockIdx.x * 64;
    int bn = blockIdx.y * 64;
    int t = threadIdx.x;
    int tr = t >> 2, tq = t & 3;
    int bkr = t >> 4, bnq = t & 15;
    int tm = (t >> 4) * 4;
    int tn = (t & 15) * 4;
    float acc[4][4] = {};
    for (int k0 = 0; k0 < K; k0 += 16) {
        int ar = bm + tr;
        float4 av = make_float4(0.f, 0.f, 0.f, 0.f);
        if (ar < M) av = *(const float4*)&A[(size_t)ar * K + k0 + tq * 4];
        As[tq * 4 + 0][tr] = av.x;
        As[tq * 4 + 1][tr] = av.y;
        As[tq * 4 + 2][tr] = av.z;
        As[tq * 4 + 3][tr] = av.w;
        float4 bv = *(const float4*)&B[(size_t)(k0 + bkr) * Nc + bn + bnq * 4];
        *(float4*)&Bs[bkr][bnq * 4] = bv;
        __syncthreads();
        #pragma unroll
        for (int k = 0; k < 16; ++k) {
            float a[4], b[4];
            *(float4*)a = *(const float4*)&As[k][tm];
            *(float4*)b = *(const float4*)&Bs[k][tn];
            #pragma unroll
            for (int i = 0; i < 4; ++i)
                #pragma unroll
                for (int j = 0; j < 4; ++j)
                    acc[i][j] = fmaf(a[i], b[j], acc[i][j]);
        }
        __syncthreads();
    }
    #pragma unroll
    for (int i = 0; i < 4; ++i) {
        int r = bm + tm + i;
        if (r < M) {
            float4 o = make_float4(acc[i][0], acc[i][1], acc[i][2], acc[i][3]);
            *(float4*)&C[(size_t)r * Nc + bn + tn] = o;
        }
    }
}

// ---------------- per-node attention coefficients ----------------

template <int HEADS, int C>
__global__ __launch_bounds__(256) void node_alpha2(const float* __restrict__ h,
                                                   const float* __restrict__ a_src,
                                                   const float* __restrict__ a_dst,
                                                   float* __restrict__ as_,
                                                   float* __restrict__ ad_) {
    constexpr int F = HEADS * C;
    constexpr int VEC = F / 64;        // 4 (F=256) or 2 (F=128)
    constexpr int LPH = C / VEC;       // lanes per head: 16 or 64
    int wid = threadIdx.x >> 6, lane = threadIdx.x & 63;
    int v = blockIdx.x * 4 + wid;
    if (v >= N_NODES) return;
    const float* hp = h + (size_t)v * F + lane * VEC;
    float ps = 0.f, pd = 0.f;
    #pragma unroll
    for (int c = 0; c < VEC; ++c) {
        float hv = hp[c];
        ps = fmaf(hv, a_src[lane * VEC + c], ps);
        pd = fmaf(hv, a_dst[lane * VEC + c], pd);
    }
    #pragma unroll
    for (int o = LPH / 2; o; o >>= 1) {
        ps += __shfl_xor(ps, o);
        pd += __shfl_xor(pd, o);
    }
    if ((lane & (LPH - 1)) == 0) {
        int head = lane / LPH;
        as_[v * HEADS + head] = ps;
        ad_[v * HEADS + head] = pd;
    }
}

// ---------------- softmax-aggregate: one wave per dst node, pipelined ------

template <int HEADS, int C, bool DO_ELU>
__global__ __launch_bounds__(256) void gat_aggregate3(
        const float* __restrict__ h,      // [N, F]
        const float* __restrict__ as_,    // [N, HEADS]
        const float* __restrict__ ad_,    // [N, HEADS]
        const int* __restrict__ row_ptr,
        const int* __restrict__ col,
        const float* __restrict__ bias,   // [F]
        float* __restrict__ out) {        // [N, F]
    constexpr int F = HEADS * C;
    constexpr int VEC = F / 64;           // 4 or 2
    constexpr int WAVES = 4;
    __shared__ int   s_off[WAVES][64];
    __shared__ float s_p[WAVES][HEADS][64];   // head-major: contiguous in k
    int wid = threadIdx.x >> 6, lane = threadIdx.x & 63;
    int v = blockIdx.x * WAVES + wid;
    if (v >= N_NODES) return;
    int head = (lane * VEC) / C;          // 4-head: lane/16 ; 1-head: 0
    int r0 = row_ptr[v], r1 = row_ptr[v + 1];
    float adh[HEADS];
    #pragma unroll
    for (int hh = 0; hh < HEADS; ++hh) adh[hh] = ad_[v * HEADS + hh];
    float acc[VEC] = {};
    float lsum[HEADS] = {};
    const char* hbl = (const char*)h + lane * VEC * 4;   // lane channel base

    for (int base = r0; base < r1; base += 64) {
        int j = base + lane;
        bool valid = j < r1;
        int s = col[valid ? j : r0];
        if (HEADS == 4) {
            float4 av = *(const float4*)&as_[s * 4];
            float ev[4] = {av.x, av.y, av.z, av.w};
            #pragma unroll
            for (int hh = 0; hh < 4; ++hh) {
                float e = ev[hh] + adh[hh];
                e = (e > 0.f) ? e : NEG_SLOPE * e;
                float p = valid ? __expf(e) : 0.f;
                lsum[hh] += p;
                s_p[wid][hh][lane] = p;
            }
        } else {
            float e = as_[s] + adh[0];
            e = (e > 0.f) ? e : NEG_SLOPE * e;
            float p = valid ? __expf(e) : 0.f;
            lsum[0] += p;
            s_p[wid][0][lane] = p;
        }
        s_off[wid][lane] = s * (F * 4);   // byte offset of row s

        int nk = min(64, r1 - base);
        int k = 0;
        // ---- pipelined main: 8 edges per step, 8 loads in flight ----
        for (; k + 8 <= nk; k += 8) {
            int offs[8];
            float pv[8];
            *(int4*)&offs[0] = *(const int4*)&s_off[wid][k];
            *(int4*)&offs[4] = *(const int4*)&s_off[wid][k + 4];
            *(float4*)&pv[0] = *(const float4*)&s_p[wid][head][k];
            *(float4*)&pv[4] = *(const float4*)&s_p[wid][head][k + 4];
            if (VEC == 4) {
                float4 hv[8];
                #pragma unroll
                for (int u = 0; u < 8; ++u)
                    hv[u] = *(const float4*)(hbl + offs[u]);
                #pragma unroll
                for (int u = 0; u < 8; ++u) {
                    acc[0] = fmaf(pv[u], hv[u].x, acc[0]);
                    acc[1] = fmaf(pv[u], hv[u].y, acc[1]);
                    acc[2] = fmaf(pv[u], hv[u].z, acc[2]);
                    acc[3] = fmaf(pv[u], hv[u].w, acc[3]);
                }
            } else {
                float2 hv[8];
                #pragma unroll
                for (int u = 0; u < 8; ++u)
                    hv[u] = *(const float2*)(hbl + offs[u]);
                #pragma unroll
                for (int u = 0; u < 8; ++u) {
                    acc[0] = fmaf(pv[u], hv[u].x, acc[0]);
                    acc[1] = fmaf(pv[u], hv[u].y, acc[1]);
                }
            }
        }
        // ---- remainder ----
        for (; k < nk; ++k) {
            int off = s_off[wid][k];
            float pk = s_p[wid][head][k];
            const float* hp = (const float*)(hbl + off);
            if (VEC == 4) {
                float4 hv = *(const float4*)hp;
                acc[0] = fmaf(pk, hv.x, acc[0]);
                acc[1] = fmaf(pk, hv.y, acc[1]);
                acc[2] = fmaf(pk, hv.z, acc[2]);
                acc[3] = fmaf(pk, hv.w, acc[3]);
            } else {
                float2 hv = *(const float2*)hp;
                acc[0] = fmaf(pk, hv.x, acc[0]);
                acc[1] = fmaf(pk, hv.y, acc[1]);
            }
        }
    }
    #pragma unroll
    for (int hh = 0; hh < HEADS; ++hh) {
        #pragma unroll
        for (int o = 32; o; o >>= 1) lsum[hh] += __shfl_xor(lsum[hh], o);
    }
    float l = lsum[0];
    if (HEADS == 4) {
        l = (head == 0) ? lsum[0] : (head == 1) ? lsum[1] : (head == 2) ? lsum[2] : lsum[3];
    }
    float inv = 1.f / (l + 1e-16f);
    #pragma unroll
    for (int c = 0; c < VEC; ++c) {
        float o = acc[c] * inv + bias[lane * VEC + c];
        if (DO_ELU) o = (o > 0.f) ? o : expm1f(o);
        out[(size_t)v * F + lane * VEC + c] = o;
    }
}

// ---------------- global mean pool: 4-way row-split + atomic combine --------

__global__ void pool_mean4(const float* __restrict__ hout, const int* __restrict__ gstart,
                           float* __restrict__ gout) {
    int g = blockIdx.x;       // 64
    int q = blockIdx.y;       // 4 row-quarters
    int c = threadIdx.x;      // 128 channels
    int off = gstart[g], end = gstart[g + 1];
    float inv = 1.f / fmaxf((float)(end - off), 1.0f);
    float s = 0.f;
    for (int i = off + q; i < end; i += 4) s += hout[(size_t)i * 128 + c];
    atomicAdd(&gout[g * 128 + c], s * inv);
}

// ---------------- launch ----------------

static inline size_t align_up(size_t x, size_t a) { return (x + a - 1) & ~(a - 1); }

extern "C" void kernel_launch(void* const* d_in, const int* in_sizes, int n_in,
                              void* d_out, int out_size, void* d_ws, size_t ws_size,
                              hipStream_t stream) {
    const float* x   = (const float*)d_in[0];
    const int*   ei  = (const int*)d_in[1];
    const int*   bat = (const int*)d_in[2];
    const float* W1  = (const float*)d_in[3];
    const float* as1 = (const float*)d_in[4];
    const float* ad1 = (const float*)d_in[5];
    const float* b1  = (const float*)d_in[6];
    const float* W2  = (const float*)d_in[7];
    const float* as2 = (const float*)d_in[8];
    const float* ad2 = (const float*)d_in[9];
    const float* b2  = (const float*)d_in[10];
    const float* W3  = (const float*)d_in[11];
    const float* as3 = (const float*)d_in[12];
    const float* ad3 = (const float*)d_in[13];
    const float* b3  = (const float*)d_in[14];

    float* gout = (float*)d_out;                     // [G,128]
    float* hout = (float*)d_out + G_GRAPHS * 128;    // [N,128]

    char* w = (char*)d_ws;
    size_t o = 0;
    float* bufA = (float*)(w + o); o = align_up(o + (size_t)N_NODES * 256 * 4, 256);
    float* bufB = (float*)(w + o); o = align_up(o + (size_t)N_NODES * 256 * 4, 256);
    float* asv  = (float*)(w + o); o = align_up(o + (size_t)N_NODES * 4 * 4, 256);
    float* adv  = (float*)(w + o); o = align_up(o + (size_t)N_NODES * 4 * 4, 256);
    int* row_ptr = (int*)(w + o);  o = align_up(o + (size_t)(N_NODES + 1) * 4, 256);
    int* col     = (int*)(w + o);  o = align_up(o + (size_t)ET_EDGES * 4, 256);
    int* cnt     = (int*)(w + o);  o += (size_t)N_NODES * 4;        // cnt+cur contiguous
    int* cur     = (int*)(w + o);  o = align_up(o + (size_t)N_NODES * 4, 256);
    int* gstart  = (int*)(w + o);  o = align_up(o + (size_t)(G_GRAPHS + 1) * 4, 256);

    // ---- CSR build + graph bounds ----
    hipMemsetAsync(cnt, 0, (size_t)N_NODES * 8, stream);   // cnt AND cur
    hipMemsetAsync(gout, 0, (size_t)G_GRAPHS * 128 * 4, stream);
    hist_dst<<<(ET_EDGES + 255) / 256, 256, 0, stream>>>(ei, cnt, bat, gstart);
    scan_rowptr<<<1, 1024, 0, stream>>>(cnt, row_ptr);
    fill_csr<<<(ET_EDGES + 255) / 256, 256, 0, stream>>>(ei, row_ptr, cur, col);

    dim3 g4(313, 4), g2(313, 2);
    int nb = (N_NODES + 3) / 4;   // 4 nodes per block

    // ---- layer 1: 128 -> 4x64 ----
    sgemm64<<<g4, 256, 0, stream>>>(x, W1, bufA, N_NODES, 128, 256);
    node_alpha2<4, 64><<<nb, 256, 0, stream>>>(bufA, as1, ad1, asv, adv);
    gat_aggregate3<4, 64, true><<<nb, 256, 0, stream>>>(bufA, asv, adv, row_ptr, col, b1, bufB);

    // ---- layer 2: 256 -> 4x64 ----
    sgemm64<<<g4, 256, 0, stream>>>(bufB, W2, bufA, N_NODES, 256, 256);
    node_alpha2<4, 64><<<nb, 256, 0, stream>>>(bufA, as2, ad2, asv, adv);
    gat_aggregate3<4, 64, true><<<nb, 256, 0, stream>>>(bufA, asv, adv, row_ptr, col, b2, bufB);

    // ---- layer 3: 256 -> 128 (1 head, no concat, no elu) ----
    sgemm64<<<g2, 256, 0, stream>>>(bufB, W3, bufA, N_NODES, 256, 128);
    node_alpha2<1, 128><<<nb, 256, 0, stream>>>(bufA, as3, ad3, asv, adv);
    gat_aggregate3<1, 128, false><<<nb, 256, 0, stream>>>(bufA, asv, adv, row_ptr, col, b3, hout);

    // ---- global mean pool ----
    pool_mean4<<<dim3(G_GRAPHS, 4), 128, 0, stream>>>(hout, gstart, gout);
}

// Round 5
// 489.993 us; speedup vs baseline: 1.3837x; 1.0608x over previous
//
#include <hip/hip_runtime.h>
#include <hip/hip_bf16.h>
#include <math.h>

#define N_NODES 20000
#define N_EDGES 640000
#define ET_EDGES (N_EDGES + N_NODES)   // with self-loops
#define G_GRAPHS 64
#define NEG_SLOPE 0.2f

// ---------------- CSR construction (+ graph bounds folded in) ----------------

__global__ void hist_dst(const int* __restrict__ ei, int* __restrict__ cnt,
                         const int* __restrict__ batch, int* __restrict__ gstart) {
    int j = blockIdx.x * blockDim.x + threadIdx.x;
    if (blockIdx.x == 0 && threadIdx.x <= G_GRAPHS) {
        int g = threadIdx.x;
        int lo = 0, hi = N_NODES;
        while (lo < hi) {              // first i with batch[i] >= g
            int mid = (lo + hi) >> 1;
            if (batch[mid] < g) lo = mid + 1; else hi = mid;
        }
        gstart[g] = lo;
    }
    if (j >= ET_EDGES) return;
    int d = (j < N_EDGES) ? ei[N_EDGES + j] : (j - N_EDGES);
    atomicAdd(&cnt[d], 1);
}

__global__ __launch_bounds__(1024) void scan_rowptr(const int* __restrict__ cnt,
                                                    int* __restrict__ row_ptr) {
    __shared__ int sums[1024];
    const int n = N_NODES;
    const int CH = (n + 1023) / 1024;   // 20
    int t = threadIdx.x;
    int base = t * CH;
    int s = 0;
    for (int i = 0; i < CH; ++i) {
        int idx = base + i;
        if (idx < n) s += cnt[idx];
    }
    sums[t] = s;
    __syncthreads();
    for (int o = 1; o < 1024; o <<= 1) {
        int v = (t >= o) ? sums[t - o] : 0;
        __syncthreads();
        sums[t] += v;
        __syncthreads();
    }
    int run = (t == 0) ? 0 : sums[t - 1];
    for (int i = 0; i < CH; ++i) {
        int idx = base + i;
        if (idx < n) { row_ptr[idx] = run; run += cnt[idx]; }
    }
    if (t == 1023) row_ptr[n] = sums[1023];
}

__global__ void fill_csr(const int* __restrict__ ei, const int* __restrict__ row_ptr,
                         int* __restrict__ cur, int* __restrict__ col) {
    int j = blockIdx.x * blockDim.x + threadIdx.x;
    if (j >= ET_EDGES) return;
    int s, d;
    if (j < N_EDGES) { s = ei[j]; d = ei[N_EDGES + j]; }
    else             { s = d = j - N_EDGES; }
    int pos = row_ptr[d] + atomicAdd(&cur[d], 1);
    col[pos] = s;
}

// ---------------- fp32 SGEMM: C[M,Nc] = A[M,K] @ B[K,Nc] ----------------

__global__ __launch_bounds__(256) void sgemm64(const float* __restrict__ A,
                                               const float* __restrict__ B,
                                               float* __restrict__ C,
                                               int M, int K, int Nc) {
    __shared__ float As[16][64];
    __shared__ float Bs[16][64];
    int bm = blockIdx.x * 64;
    int bn = blockIdx.y * 64;
    int t = threadIdx.x;
    int tr = t >> 2, tq = t & 3;
    int bkr = t >> 4, bnq = t & 15;
    int tm = (t >> 4) * 4;
    int tn = (t & 15) * 4;
    float acc[4][4] = {};
    for (int k0 = 0; k0 < K; k0 += 16) {
        int ar = bm + tr;
        float4 av = make_float4(0.f, 0.f, 0.f, 0.f);
        if (ar < M) av = *(const float4*)&A[(size_t)ar * K + k0 + tq * 4];
        As[tq * 4 + 0][tr] = av.x;
        As[tq * 4 + 1][tr] = av.y;
        As[tq * 4 + 2][tr] = av.z;
        As[tq * 4 + 3][tr] = av.w;
        float4 bv = *(const float4*)&B[(size_t)(k0 + bkr) * Nc + bn + bnq * 4];
        *(float4*)&Bs[bkr][bnq * 4] = bv;
        __syncthreads();
        #pragma unroll
        for (int k = 0; k < 16; ++k) {
            float a[4], b[4];
            *(float4*)a = *(const float4*)&As[k][tm];
            *(float4*)b = *(const float4*)&Bs[k][tn];
            #pragma unroll
            for (int i = 0; i < 4; ++i)
                #pragma unroll
                for (int j = 0; j < 4; ++j)
                    acc[i][j] = fmaf(a[i], b[j], acc[i][j]);
        }
        __syncthreads();
    }
    #pragma unroll
    for (int i = 0; i < 4; ++i) {
        int r = bm + tm + i;
        if (r < M) {
            float4 o = make_float4(acc[i][0], acc[i][1], acc[i][2], acc[i][3]);
            *(float4*)&C[(size_t)r * Nc + bn + tn] = o;
        }
    }
}

// ---------------- per-node attention coefficients (transposed out) ---------

template <int HEADS, int C>
__global__ __launch_bounds__(256) void node_alpha2(const float* __restrict__ h,
                                                   const float* __restrict__ a_src,
                                                   const float* __restrict__ a_dst,
                                                   float* __restrict__ asT,   // [HEADS][N]
                                                   float* __restrict__ adT) { // [HEADS][N]
    constexpr int F = HEADS * C;
    constexpr int VEC = F / 64;        // 4 (F=256) or 2 (F=128)
    constexpr int LPH = C / VEC;       // lanes per head: 16 or 64
    int wid = threadIdx.x >> 6, lane = threadIdx.x & 63;
    int v = blockIdx.x * 4 + wid;
    if (v >= N_NODES) return;
    const float* hp = h + (size_t)v * F + lane * VEC;
    float ps = 0.f, pd = 0.f;
    #pragma unroll
    for (int c = 0; c < VEC; ++c) {
        float hv = hp[c];
        ps = fmaf(hv, a_src[lane * VEC + c], ps);
        pd = fmaf(hv, a_dst[lane * VEC + c], pd);
    }
    #pragma unroll
    for (int o = LPH / 2; o; o >>= 1) {
        ps += __shfl_xor(ps, o);
        pd += __shfl_xor(pd, o);
    }
    if ((lane & (LPH - 1)) == 0) {
        int head = lane / LPH;
        asT[head * N_NODES + v] = ps;
        adT[head * N_NODES + v] = pd;
    }
}

// ---------------- channel-sliced softmax-aggregate -------------------------
// Wave = (dst node, channel slice). NSLICE=4 slices; slice = blockIdx.x & 3 so
// (with the %8 round-robin dispatch heuristic) slice s lands only on XCDs
// {s, s+4}: per-XCD L2 working set = N * SCH * 4 B (5 MB / 2.5 MB) instead of
// the whole 20 MB table. E edges processed in parallel per wave; lane =
// (edge_group, channel_lane), 16 B/lane gathers preserved.

template <int NSLICE, int SCH, int F, int HEADS, bool DO_ELU>
__global__ __launch_bounds__(256) void gat_aggregate_sliced(
        const float* __restrict__ h,      // [N, F]
        const float* __restrict__ asT,    // [HEADS][N]
        const float* __restrict__ adT,    // [HEADS][N]
        const int* __restrict__ row_ptr,
        const int* __restrict__ col,
        const float* __restrict__ bias,   // [F]
        float* __restrict__ out) {        // [N, F]
    constexpr int CL = SCH / 4;           // lanes per edge (16 or 8)
    constexpr int E  = 64 / CL;           // parallel edges (4 or 8)
    constexpr int CPH = F / HEADS;        // channels per head
    __shared__ int   s_off[4][64];
    __shared__ float s_p[4][64];
    int slice = blockIdx.x & (NSLICE - 1);
    int ng = blockIdx.x >> 2;             // NSLICE == 4
    int wid = threadIdx.x >> 6, lane = threadIdx.x & 63;
    int v = ng * 4 + wid;
    if (v >= N_NODES) return;
    int head = (slice * SCH) / CPH;       // layers 1/2: slice == head; layer 3: 0
    int eg = lane / CL, cl = lane % CL;
    int r0 = row_ptr[v], r1 = row_ptr[v + 1];
    float ad = adT[head * N_NODES + v];
    const float* asrc = asT + head * N_NODES;
    float acc[4] = {};
    float lsum = 0.f;
    const char* hb = (const char*)(h + slice * SCH + cl * 4);

    for (int base = r0; base < r1; base += 64) {
        int j = base + lane;
        bool valid = j < r1;
        int s = col[valid ? j : r0];
        float e = asrc[s] + ad;
        e = (e > 0.f) ? e : NEG_SLOPE * e;
        float p = valid ? __expf(e) : 0.f;
        lsum += p;
        s_p[wid][lane] = p;
        s_off[wid][lane] = s * (F * 4);   // byte offset of row s

        int nk = min(64, r1 - base);
        int nkg = (nk + E - 1) / E;
        for (int g = 0; g < nkg; ++g) {
            int k = g * E + eg;
            float pk = s_p[wid][k];       // broadcast across CL lanes
            int off = s_off[wid][k];
            float4 hv = *(const float4*)(hb + off);
            acc[0] = fmaf(pk, hv.x, acc[0]);
            acc[1] = fmaf(pk, hv.y, acc[1]);
            acc[2] = fmaf(pk, hv.z, acc[2]);
            acc[3] = fmaf(pk, hv.w, acc[3]);
        }
    }
    // full-wave softmax denominator
    #pragma unroll
    for (int o = 32; o; o >>= 1) lsum += __shfl_xor(lsum, o);
    // reduce acc across edge groups (lanes differing in bits >= log2(CL))
    #pragma unroll
    for (int c = 0; c < 4; ++c) {
        #pragma unroll
        for (int o = CL; o < 64; o <<= 1) acc[c] += __shfl_xor(acc[c], o);
    }
    if (eg == 0) {
        float inv = 1.f / (lsum + 1e-16f);
        #pragma unroll
        for (int c = 0; c < 4; ++c) {
            int ch = slice * SCH + cl * 4 + c;
            float o = acc[c] * inv + bias[ch];
            if (DO_ELU) o = (o > 0.f) ? o : expm1f(o);
            out[(size_t)v * F + ch] = o;
        }
    }
}

// ---------------- global mean pool: 4-way row-split + atomic combine --------

__global__ void pool_mean4(const float* __restrict__ hout, const int* __restrict__ gstart,
                           float* __restrict__ gout) {
    int g = blockIdx.x;       // 64
    int q = blockIdx.y;       // 4 row-quarters
    int c = threadIdx.x;      // 128 channels
    int off = gstart[g], end = gstart[g + 1];
    float inv = 1.f / fmaxf((float)(end - off), 1.0f);
    float s = 0.f;
    for (int i = off + q; i < end; i += 4) s += hout[(size_t)i * 128 + c];
    atomicAdd(&gout[g * 128 + c], s * inv);
}

// ---------------- launch ----------------

static inline size_t align_up(size_t x, size_t a) { return (x + a - 1) & ~(a - 1); }

extern "C" void kernel_launch(void* const* d_in, const int* in_sizes, int n_in,
                              void* d_out, int out_size, void* d_ws, size_t ws_size,
                              hipStream_t stream) {
    const float* x   = (const float*)d_in[0];
    const int*   ei  = (const int*)d_in[1];
    const int*   bat = (const int*)d_in[2];
    const float* W1  = (const float*)d_in[3];
    const float* as1 = (const float*)d_in[4];
    const float* ad1 = (const float*)d_in[5];
    const float* b1  = (const float*)d_in[6];
    const float* W2  = (const float*)d_in[7];
    const float* as2 = (const float*)d_in[8];
    const float* ad2 = (const float*)d_in[9];
    const float* b2  = (const float*)d_in[10];
    const float* W3  = (const float*)d_in[11];
    const float* as3 = (const float*)d_in[12];
    const float* ad3 = (const float*)d_in[13];
    const float* b3  = (const float*)d_in[14];

    float* gout = (float*)d_out;                     // [G,128]
    float* hout = (float*)d_out + G_GRAPHS * 128;    // [N,128]

    char* w = (char*)d_ws;
    size_t o = 0;
    float* bufA = (float*)(w + o); o = align_up(o + (size_t)N_NODES * 256 * 4, 256);
    float* bufB = (float*)(w + o); o = align_up(o + (size_t)N_NODES * 256 * 4, 256);
    float* asv  = (float*)(w + o); o = align_up(o + (size_t)N_NODES * 4 * 4, 256);
    float* adv  = (float*)(w + o); o = align_up(o + (size_t)N_NODES * 4 * 4, 256);
    int* row_ptr = (int*)(w + o);  o = align_up(o + (size_t)(N_NODES + 1) * 4, 256);
    int* col     = (int*)(w + o);  o = align_up(o + (size_t)ET_EDGES * 4, 256);
    int* cnt     = (int*)(w + o);  o += (size_t)N_NODES * 4;        // cnt+cur contiguous
    int* cur     = (int*)(w + o);  o = align_up(o + (size_t)N_NODES * 4, 256);
    int* gstart  = (int*)(w + o);  o = align_up(o + (size_t)(G_GRAPHS + 1) * 4, 256);

    // ---- CSR build + graph bounds ----
    hipMemsetAsync(cnt, 0, (size_t)N_NODES * 8, stream);   // cnt AND cur
    hipMemsetAsync(gout, 0, (size_t)G_GRAPHS * 128 * 4, stream);
    hist_dst<<<(ET_EDGES + 255) / 256, 256, 0, stream>>>(ei, cnt, bat, gstart);
    scan_rowptr<<<1, 1024, 0, stream>>>(cnt, row_ptr);
    fill_csr<<<(ET_EDGES + 255) / 256, 256, 0, stream>>>(ei, row_ptr, cur, col);

    dim3 g4(313, 4), g2(313, 2);
    int nb = (N_NODES + 3) / 4;   // 4 nodes per block
    int nbs = nb * 4;             // x4 channel slices

    // ---- layer 1: 128 -> 4x64 ----
    sgemm64<<<g4, 256, 0, stream>>>(x, W1, bufA, N_NODES, 128, 256);
    node_alpha2<4, 64><<<nb, 256, 0, stream>>>(bufA, as1, ad1, asv, adv);
    gat_aggregate_sliced<4, 64, 256, 4, true><<<nbs, 256, 0, stream>>>(
        bufA, asv, adv, row_ptr, col, b1, bufB);

    // ---- layer 2: 256 -> 4x64 ----
    sgemm64<<<g4, 256, 0, stream>>>(bufB, W2, bufA, N_NODES, 256, 256);
    node_alpha2<4, 64><<<nb, 256, 0, stream>>>(bufA, as2, ad2, asv, adv);
    gat_aggregate_sliced<4, 64, 256, 4, true><<<nbs, 256, 0, stream>>>(
        bufA, asv, adv, row_ptr, col, b2, bufB);

    // ---- layer 3: 256 -> 128 (1 head, no concat, no elu) ----
    sgemm64<<<g2, 256, 0, stream>>>(bufB, W3, bufA, N_NODES, 256, 128);
    node_alpha2<1, 128><<<nb, 256, 0, stream>>>(bufA, as3, ad3, asv, adv);
    gat_aggregate_sliced<4, 32, 128, 1, false><<<nbs, 256, 0, stream>>>(
        bufA, asv, adv, row_ptr, col, b3, hout);

    // ---- global mean pool ----
    pool_mean4<<<dim3(G_GRAPHS, 4), 128, 0, stream>>>(hout, gstart, gout);
}